// Round 4
// baseline (1155.090 us; speedup 1.0000x reference)
//
#include <hip/hip_runtime.h>

#define B_ 4
#define N_ 4096
#define D_ 1024
#define E_ 8
#define TOPK_ 2

typedef float f32x4 __attribute__((ext_vector_type(4)));  // native clang vector: OK for nontemporal builtins

// ws layout (bytes):
//   [0,       131072)  idx  int[B*N*2]   top-2 expert indices
//   [131072,  262144)  pri  int[B*N*2]   per-slot priority (rank in expert queue)
//   [262144,  393216)  gp   float[B*N*2] probs of chosen experts
//   [393216,  393476)  acc  float[65]    zsum, psum[4*8], cnt[4*8]

__global__ __launch_bounds__(256) void k_router_gemm(
    const float* __restrict__ x,     // [B,N,D]
    const float* __restrict__ w,     // [D,E] row-major
    int*   __restrict__ idx_out,     // [B*N*2]
    float* __restrict__ gp_out,      // [B*N*2]
    float* __restrict__ acc)         // [65]
{
    __shared__ float Wt[E_][D_];     // 32 KB, transposed gate
    __shared__ float psumL[B_][E_];
    __shared__ float cntL[B_][E_];
    __shared__ float zL;
    const int tid = threadIdx.x;

    for (int i = tid; i < D_ * E_; i += 256) Wt[i & 7][i >> 3] = w[i];
    if (tid < B_ * E_) { psumL[tid >> 3][tid & 7] = 0.f; cntL[tid >> 3][tid & 7] = 0.f; }
    if (tid == 0) zL = 0.f;
    __syncthreads();

    const int lane = tid & 63;
    const int gw   = blockIdx.x * 4 + (tid >> 6);
    const int nw   = gridDim.x * 4;

    for (int t = gw; t < B_ * N_; t += nw) {
        const int b = t >> 12;
        const float* xp = x + (size_t)t * D_;
        float a[E_];
        #pragma unroll
        for (int e = 0; e < E_; ++e) a[e] = 0.f;

        #pragma unroll
        for (int j = 0; j < D_ / 64; ++j) {
            const int d = j * 64 + lane;          // coalesced 256B token read
            const float tv = xp[d];
            #pragma unroll
            for (int e = 0; e < E_; ++e) a[e] += tv * Wt[e][d];  // bank = lane%32: 2-way, free
        }
        // 64-lane butterfly reduce, all lanes end with full logits
        #pragma unroll
        for (int e = 0; e < E_; ++e) {
            float v = a[e];
            #pragma unroll
            for (int off = 32; off >= 1; off >>= 1) v += __shfl_xor(v, off);
            a[e] = v;
        }
        // softmax + logsumexp (redundant on all lanes, uniform)
        float m = a[0];
        #pragma unroll
        for (int e = 1; e < E_; ++e) m = fmaxf(m, a[e]);
        float ex[E_], s = 0.f;
        #pragma unroll
        for (int e = 0; e < E_; ++e) { ex[e] = expf(a[e] - m); s += ex[e]; }
        const float inv = 1.f / s;
        float p[E_];
        #pragma unroll
        for (int e = 0; e < E_; ++e) p[e] = ex[e] * inv;
        const float z = m + logf(s);

        // top-2 on probs, ties -> lowest index (strict > keeps first max)
        int i1 = 0; float p1 = p[0];
        #pragma unroll
        for (int e = 1; e < E_; ++e) if (p[e] > p1) { p1 = p[e]; i1 = e; }
        int i2 = (i1 == 0) ? 1 : 0; float p2 = p[i2];
        #pragma unroll
        for (int e = 0; e < E_; ++e) if (e != i1 && p[e] > p2) { p2 = p[e]; i2 = e; }

        if (lane == 0) {
            idx_out[t * 2]     = i1;
            idx_out[t * 2 + 1] = i2;
            gp_out[t * 2]      = p1;
            gp_out[t * 2 + 1]  = p2;
            atomicAdd(&zL, z * z);
        }
        if (lane < E_) {
            atomicAdd(&psumL[b][lane], p[lane]);
            if (lane == i1 || lane == i2) atomicAdd(&cntL[b][lane], 1.f);
        }
    }
    __syncthreads();
    if (tid == 0) atomicAdd(&acc[0], zL);
    if (tid < 32) atomicAdd(&acc[1 + tid], psumL[tid >> 3][tid & 7]);
    if (tid >= 32 && tid < 64) { int q = tid - 32; atomicAdd(&acc[33 + q], cntL[q >> 3][q & 7]); }
}

// One wave per batch: sequential chunked scan over the topk-major stream
// p = k*N + n, rank = #(earlier slots in stream with same expert).
__global__ __launch_bounds__(64) void k_router_priority(
    const int* __restrict__ idx,     // [B*N*2]
    int*       __restrict__ pri,     // [B*N*2]
    const float* __restrict__ acc,   // [65]
    float*     __restrict__ out_scalars)  // d_out tail: aux_loss, z_loss
{
    const int b = blockIdx.x;
    const int lane = threadIdx.x;
    int run[E_];
    #pragma unroll
    for (int q = 0; q < E_; ++q) run[q] = 0;

    const unsigned long long below_mask = (lane == 0) ? 0ull : (~0ull >> (64 - lane));

    // loads are address-independent of the ballot chain; unroll lets the
    // compiler hoist them past the serial run[] accumulation
    #pragma unroll 4
    for (int it = 0; it < (TOPK_ * N_) / 64; ++it) {
        const int p = it * 64 + lane;
        const int k = p >> 12;           // p / N
        const int n = p & (N_ - 1);
        const int e = idx[((size_t)b * N_ + n) * 2 + k];
        int myrank = 0;
        #pragma unroll
        for (int q = 0; q < E_; ++q) {
            const unsigned long long mask = __ballot(e == q);
            if (e == q) myrank = run[q] + __popcll(mask & below_mask);
            run[q] += __popcll(mask);
        }
        pri[((size_t)b * N_ + n) * 2 + k] = myrank;
    }

    if (b == 0 && lane == 0) {
        const float zmean = acc[0] / (float)(B_ * N_);
        float auxv = 0.f;
        #pragma unroll
        for (int i = 0; i < B_ * E_; ++i)
            auxv += (acc[1 + i] / (float)N_) * (acc[33 + i] / (float)N_);
        auxv = auxv / (float)(B_ * E_) * (float)(E_ * E_);
        out_scalars[0] = auxv;   // aux_loss
        out_scalars[1] = zmean;  // z_loss
    }
}

// One block per token: write its [E][C] plane in dispatch and combine.
// Branch-free per-component selects (no runtime vector indexing -> no scratch).
__global__ __launch_bounds__(256) void k_router_fill(
    const int* __restrict__ idx,
    const int* __restrict__ pri,
    const float* __restrict__ gp,
    float* __restrict__ out, int cap)
{
    const size_t t = blockIdx.x;
    const int tid = threadIdx.x;
    const int e0 = idx[t * 2],     e1 = idx[t * 2 + 1];
    const int p0 = pri[t * 2],     p1 = pri[t * 2 + 1];
    const float g0 = gp[t * 2],    g1 = gp[t * 2 + 1];
    const int hot0 = (p0 < cap) ? (e0 * cap + p0) : -1;
    const int hot1 = (p1 < cap) ? (e1 * cap + p1) : -1;

    const size_t planesz = (size_t)E_ * (size_t)cap;          // 8192 floats
    f32x4* disp = (f32x4*)(out + t * planesz);
    f32x4* comb = (f32x4*)(out + (size_t)B_ * N_ * planesz + t * planesz);
    const int nvec = (int)(planesz >> 2);                     // 2048

    for (int f = tid; f < nvec; f += 256) {
        const int base = f << 2;
        f32x4 vd, vc;
        // component c is hot iff hot0==base+c or hot1==base+c (hot0!=hot1 since e0!=e1)
        const bool h00 = (hot0 == base + 0), h10 = (hot1 == base + 0);
        const bool h01 = (hot0 == base + 1), h11 = (hot1 == base + 1);
        const bool h02 = (hot0 == base + 2), h12 = (hot1 == base + 2);
        const bool h03 = (hot0 == base + 3), h13 = (hot1 == base + 3);
        vd.x = (h00 | h10) ? 1.f : 0.f;  vc.x = h00 ? g0 : (h10 ? g1 : 0.f);
        vd.y = (h01 | h11) ? 1.f : 0.f;  vc.y = h01 ? g0 : (h11 ? g1 : 0.f);
        vd.z = (h02 | h12) ? 1.f : 0.f;  vc.z = h02 ? g0 : (h12 ? g1 : 0.f);
        vd.w = (h03 | h13) ? 1.f : 0.f;  vc.w = h03 ? g0 : (h13 ? g1 : 0.f);
        __builtin_nontemporal_store(vd, &disp[f]);
        __builtin_nontemporal_store(vc, &comb[f]);
    }
}

extern "C" void kernel_launch(void* const* d_in, const int* in_sizes, int n_in,
                              void* d_out, int out_size, void* d_ws, size_t ws_size,
                              hipStream_t stream) {
    const float* x = (const float*)d_in[0];
    const float* w = (const float*)d_in[1];
    // capacity from out_size: out = 2*B*N*E*C + 2 scalars
    const long long C = ((long long)out_size - 2) / ((long long)B_ * N_ * E_ * 2);

    char* ws = (char*)d_ws;
    int*   idx = (int*)(ws);
    int*   pri = (int*)(ws + 131072);
    float* gp  = (float*)(ws + 262144);
    float* acc = (float*)(ws + 393216);

    (void)hipMemsetAsync(acc, 0, 65 * sizeof(float), stream);

    // 1024 blocks x 4 waves = 4 waves/SIMD (4 blocks/CU, 128KB/160KB LDS): latency hiding
    k_router_gemm<<<1024, 256, 0, stream>>>(x, w, idx, gp, acc);

    float* out_scalars = (float*)d_out + (size_t)B_ * N_ * E_ * C * 2;
    k_router_priority<<<B_, 64, 0, stream>>>(idx, pri, acc, out_scalars);

    k_router_fill<<<B_ * N_, 256, 0, stream>>>(idx, pri, gp, (float*)d_out, (int)C);
}

// Round 5
// 1126.517 us; speedup vs baseline: 1.0254x; 1.0254x over previous
//
#include <hip/hip_runtime.h>

#define B_ 4
#define N_ 4096
#define D_ 1024
#define E_ 8
#define TOPK_ 2

// ws layout (bytes):
//   [0,       131072)  idx  int[B*N*2]   top-2 expert indices
//   [131072,  262144)  pri  int[B*N*2]   per-slot priority (rank in expert queue)
//   [262144,  393216)  gp   float[B*N*2] probs of chosen experts
//   [393216,  393476)  acc  float[65]    zsum, psum[4*8], cnt[4*8]

__global__ __launch_bounds__(256) void k_router_gemm(
    const float* __restrict__ x,     // [B,N,D]
    const float* __restrict__ w,     // [D,E] row-major
    int*   __restrict__ idx_out,     // [B*N*2]
    float* __restrict__ gp_out,      // [B*N*2]
    float* __restrict__ acc)         // [65]
{
    __shared__ float Wt[E_][D_];     // 32 KB, transposed gate
    __shared__ float psumL[B_][E_];
    __shared__ float cntL[B_][E_];
    __shared__ float zL;
    const int tid = threadIdx.x;

    for (int i = tid; i < D_ * E_; i += 256) Wt[i & 7][i >> 3] = w[i];
    if (tid < B_ * E_) { psumL[tid >> 3][tid & 7] = 0.f; cntL[tid >> 3][tid & 7] = 0.f; }
    if (tid == 0) zL = 0.f;
    __syncthreads();

    const int lane = tid & 63;
    const int gw   = blockIdx.x * 4 + (tid >> 6);
    const int nw   = gridDim.x * 4;

    for (int t = gw; t < B_ * N_; t += nw) {
        const int b = t >> 12;
        const float* xp = x + (size_t)t * D_;
        float a[E_];
        #pragma unroll
        for (int e = 0; e < E_; ++e) a[e] = 0.f;

        #pragma unroll
        for (int j = 0; j < D_ / 64; ++j) {
            const int d = j * 64 + lane;          // coalesced 256B token read
            const float tv = xp[d];
            #pragma unroll
            for (int e = 0; e < E_; ++e) a[e] += tv * Wt[e][d];  // bank = lane%32: 2-way, free
        }
        // 64-lane butterfly reduce, all lanes end with full logits
        #pragma unroll
        for (int e = 0; e < E_; ++e) {
            float v = a[e];
            #pragma unroll
            for (int off = 32; off >= 1; off >>= 1) v += __shfl_xor(v, off);
            a[e] = v;
        }
        // softmax + logsumexp (redundant on all lanes, uniform)
        float m = a[0];
        #pragma unroll
        for (int e = 1; e < E_; ++e) m = fmaxf(m, a[e]);
        float ex[E_], s = 0.f;
        #pragma unroll
        for (int e = 0; e < E_; ++e) { ex[e] = expf(a[e] - m); s += ex[e]; }
        const float inv = 1.f / s;
        float p[E_];
        #pragma unroll
        for (int e = 0; e < E_; ++e) p[e] = ex[e] * inv;
        const float z = m + logf(s);

        // top-2 on probs, ties -> lowest index (strict > keeps first max)
        int i1 = 0; float p1 = p[0];
        #pragma unroll
        for (int e = 1; e < E_; ++e) if (p[e] > p1) { p1 = p[e]; i1 = e; }
        int i2 = (i1 == 0) ? 1 : 0; float p2 = p[i2];
        #pragma unroll
        for (int e = 0; e < E_; ++e) if (e != i1 && p[e] > p2) { p2 = p[e]; i2 = e; }

        if (lane == 0) {
            idx_out[t * 2]     = i1;
            idx_out[t * 2 + 1] = i2;
            gp_out[t * 2]      = p1;
            gp_out[t * 2 + 1]  = p2;
            atomicAdd(&zL, z * z);
        }
        if (lane < E_) {
            atomicAdd(&psumL[b][lane], p[lane]);
            if (lane == i1 || lane == i2) atomicAdd(&cntL[b][lane], 1.f);
        }
    }
    __syncthreads();
    if (tid == 0) atomicAdd(&acc[0], zL);
    if (tid < 32) atomicAdd(&acc[1 + tid], psumL[tid >> 3][tid & 7]);
    if (tid >= 32 && tid < 64) { int q = tid - 32; atomicAdd(&acc[33 + q], cntL[q >> 3][q & 7]); }
}

// One wave per batch: sequential chunked scan over the topk-major stream
// p = k*N + n, rank = #(earlier slots in stream with same expert).
__global__ __launch_bounds__(64) void k_router_priority(
    const int* __restrict__ idx,     // [B*N*2]
    int*       __restrict__ pri,     // [B*N*2]
    const float* __restrict__ acc,   // [65]
    float*     __restrict__ out_scalars)  // d_out tail: aux_loss, z_loss
{
    const int b = blockIdx.x;
    const int lane = threadIdx.x;
    int run[E_];
    #pragma unroll
    for (int q = 0; q < E_; ++q) run[q] = 0;

    const unsigned long long below_mask = (lane == 0) ? 0ull : (~0ull >> (64 - lane));

    // loads are address-independent of the ballot chain; unroll lets the
    // compiler hoist them past the serial run[] accumulation
    #pragma unroll 4
    for (int it = 0; it < (TOPK_ * N_) / 64; ++it) {
        const int p = it * 64 + lane;
        const int k = p >> 12;           // p / N
        const int n = p & (N_ - 1);
        const int e = idx[((size_t)b * N_ + n) * 2 + k];
        int myrank = 0;
        #pragma unroll
        for (int q = 0; q < E_; ++q) {
            const unsigned long long mask = __ballot(e == q);
            if (e == q) myrank = run[q] + __popcll(mask & below_mask);
            run[q] += __popcll(mask);
        }
        pri[((size_t)b * N_ + n) * 2 + k] = myrank;
    }

    if (b == 0 && lane == 0) {
        const float zmean = acc[0] / (float)(B_ * N_);
        float auxv = 0.f;
        #pragma unroll
        for (int i = 0; i < B_ * E_; ++i)
            auxv += (acc[1 + i] / (float)N_) * (acc[33 + i] / (float)N_);
        auxv = auxv / (float)(B_ * E_) * (float)(E_ * E_);
        out_scalars[0] = auxv;   // aux_loss
        out_scalars[1] = zmean;  // z_loss
    }
}

// Sparse hot-entry scatter: d_out was already zeroed by hipMemsetAsync.
// One thread per (token, k-slot): at most 2 writes per tensor per token.
// e0 != e1 within a token, so no address collisions.
__global__ __launch_bounds__(256) void k_scatter(
    const int* __restrict__ idx,
    const int* __restrict__ pri,
    const float* __restrict__ gp,
    float* __restrict__ out, int cap)
{
    const int s = blockIdx.x * 256 + threadIdx.x;   // 0 .. B*N*2-1
    if (s >= B_ * N_ * TOPK_) return;
    const int t = s >> 1;
    const int e = idx[s];
    const int p = pri[s];
    if (p < cap) {
        const size_t planesz = (size_t)E_ * (size_t)cap;
        const size_t off = (size_t)t * planesz + (size_t)e * cap + p;
        out[off] = 1.f;                                      // dispatch
        out[(size_t)B_ * N_ * planesz + off] = gp[s];        // combine
    }
}

extern "C" void kernel_launch(void* const* d_in, const int* in_sizes, int n_in,
                              void* d_out, int out_size, void* d_ws, size_t ws_size,
                              hipStream_t stream) {
    const float* x = (const float*)d_in[0];
    const float* w = (const float*)d_in[1];
    // capacity from out_size: out = 2*B*N*E*C + 2 scalars
    const long long C = ((long long)out_size - 2) / ((long long)B_ * N_ * E_ * 2);

    char* ws = (char*)d_ws;
    int*   idx = (int*)(ws);
    int*   pri = (int*)(ws + 131072);
    float* gp  = (float*)(ws + 262144);
    float* acc = (float*)(ws + 393216);

    // Bulk-zero the whole output (incl. scalar slots) on the rocclr fill path
    // (measured 6.3 TB/s on this chip), then scatter only the hot entries.
    (void)hipMemsetAsync(d_out, 0, (size_t)out_size * sizeof(float), stream);
    (void)hipMemsetAsync(acc, 0, 65 * sizeof(float), stream);

    // 1024 blocks x 4 waves = 4 waves/SIMD (4 blocks/CU, 128KB/160KB LDS): latency hiding
    k_router_gemm<<<1024, 256, 0, stream>>>(x, w, idx, gp, acc);

    float* out_scalars = (float*)d_out + (size_t)B_ * N_ * E_ * C * 2;
    k_router_priority<<<B_, 64, 0, stream>>>(idx, pri, acc, out_scalars);

    k_scatter<<<(B_ * N_ * TOPK_ + 255) / 256, 256, 0, stream>>>(idx, pri, gp, (float*)d_out, (int)C);
}